// Round 12
// baseline (77.683 us; speedup 1.0000x reference)
//
#include <hip/hip_runtime.h>

// Hausdorff adv2ori via MFMA: B=8, K=8192.
// dist(n,m) = oo_n + aa_m - 2*o.a ; C = mfma(A',B') = oo_n - 2*o.a (fp16 hi/lo split)
// loss = mean_b( w_b * max_m min_n dist )
//
// R11 post-mortem: pipelining showed no gain BUT it also shortened the A-frag
// prefetch distance from a full iteration (R10) to ~16 instrs -> re-exposed
// ~60-90cyc LDS latency/tile, masking the interleave. Separately, R9's
// MfmaUtil=42% with exactly-right matrix *demand* says the pipe idles because
// identical lockstep blocks phase-align their MFMA bursts per SIMD.
// R12: (1) full-iteration prefetch distance restored + fold/MFMA interleave;
// (2) per-block tile-order rotation rho(t) = t ^ k8, k8 = hash(bid) in
//     {0,8,16,24} -> co-resident blocks hit the matrix pipe ~800cyc apart
//     (fmin exactly associative -> bit-identical result);
// (3) s_setprio(1) around MFMA pairs (T5; phase diversity now exists).

#define KPTS 8192
#define BATCH 8
#define NSPLIT 8
#define RBLK (KPTS / NSPLIT)          // 1024 rows per slice
#define TSLICE (RBLK / 32)            // 32 MFMA row-tiles per slice
#define CBLK 512                      // adv columns per block (4 waves x 128)
#define MCHUNK (KPTS / CBLK)          // 16

typedef _Float16 half8 __attribute__((ext_vector_type(8)));
typedef float f32x16 __attribute__((ext_vector_type(16)));

// rm = min(rm, c[0..15]) in exactly 8 v_min3_f32 (3-ary tree over 17 leaves).
#define FOLD17(rm, c)                                                         \
    do {                                                                      \
        float t0_, t1_, t2_, t3_, t4_, t5_, t6_, o_;                          \
        asm volatile(                                                         \
            "v_min3_f32 %0, %8, %9, %10\n\t"                                  \
            "v_min3_f32 %1, %11, %12, %13\n\t"                                \
            "v_min3_f32 %2, %14, %15, %16\n\t"                                \
            "v_min3_f32 %3, %17, %18, %19\n\t"                                \
            "v_min3_f32 %4, %20, %21, %22\n\t"                                \
            "v_min3_f32 %5, %23, %24, %0\n\t"                                 \
            "v_min3_f32 %6, %1, %2, %3\n\t"                                   \
            "v_min3_f32 %7, %4, %5, %6"                                       \
            : "=&v"(t0_), "=&v"(t1_), "=&v"(t2_), "=&v"(t3_), "=&v"(t4_),     \
              "=&v"(t5_), "=v"(t6_), "=v"(o_)                                 \
            : "v"((c)[0]), "v"((c)[1]), "v"((c)[2]), "v"((c)[3]),             \
              "v"((c)[4]), "v"((c)[5]), "v"((c)[6]), "v"((c)[7]),             \
              "v"((c)[8]), "v"((c)[9]), "v"((c)[10]), "v"((c)[11]),           \
              "v"((c)[12]), "v"((c)[13]), "v"((c)[14]), "v"((c)[15]),         \
              "v"(rm));                                                       \
        (rm) = o_;                                                            \
    } while (0)

// Two MFMAs bracketed by setprio (T5): favored while the matrix pipe is fed.
#define MFMA2P(d_a, d_b, af_, bfa, bfb, zc_)                                  \
    asm volatile(                                                             \
        "s_setprio 1\n\t"                                                     \
        "v_mfma_f32_32x32x16_f16 %0, %2, %3, %5\n\t"                          \
        "v_mfma_f32_32x32x16_f16 %1, %2, %4, %5\n\t"                          \
        "s_setprio 0"                                                         \
        : "=&v"(d_a), "=&v"(d_b)                                              \
        : "v"(af_), "v"(bfa), "v"(bfb), "v"(zc_))

__global__ __launch_bounds__(256, 4) void hausdorff(const float* __restrict__ adv,
                                                    const float* __restrict__ ori,
                                                    float* __restrict__ part,
                                                    float* __restrict__ out) {
    // Tile-planar A' slice: tile t at bytes [t*1024,(t+1)*1024); lane reads
    // byte lane*16 -> linear, conflict-free.
    __shared__ _Float16 sA[TSLICE * 512];   // 32 KB -> 4 blocks/CU

    const int bid  = blockIdx.x;          // grid = 8 * 16 * 8 = 1024
    const int b    = bid >> 7;
    const int mc   = (bid >> 3) & (MCHUNK - 1);
    const int ns   = bid & 7;
    const int tid  = threadIdx.x;
    const int lane = tid & 63;
    const int wv   = tid >> 6;
    const int r    = lane & 31;
    const int hk   = lane >> 5;

    if (bid == 0 && tid == 0) out[0] = 0.0f;   // for reduceB's atomicAdd

    const _Float16 Z = (_Float16)0.0f, ONE = (_Float16)1.0f;

    // ---- B-fragments + aa for this wave's 4 column groups ----
    const float* advb = adv + (size_t)b * KPTS * 3;
    const int m0 = mc * CBLK + wv * 128 + r;
    half8 bf0, bf1, bf2, bf3;
    float aa0, aa1, aa2, aa3;
#pragma unroll
    for (int i = 0; i < 4; ++i) {
        const int m = m0 + 32 * i;
        float ax = advb[3 * m], ay = advb[3 * m + 1], az = advb[3 * m + 2];
        float aa = ax * ax + ay * ay + az * az;
        float tx = -2.f * ax, ty = -2.f * ay, tz = -2.f * az;
        _Float16 bx = (_Float16)tx, by = (_Float16)ty, bz = (_Float16)tz;
        _Float16 cx = (_Float16)(tx - (float)bx);
        _Float16 cy = (_Float16)(ty - (float)by);
        _Float16 cz = (_Float16)(tz - (float)bz);
        half8 h0 = {bx, by, bz, cx, cy, cz, bx, by};
        half8 h1 = {bz, ONE, ONE, Z, Z, Z, Z, Z};
        half8 bi = hk ? h1 : h0;
        if (i == 0) { bf0 = bi; aa0 = aa; }
        else if (i == 1) { bf1 = bi; aa1 = aa; }
        else if (i == 2) { bf2 = bi; aa2 = aa; }
        else { bf3 = bi; aa3 = aa; }
    }

    // ---- stage + convert this block's 1024-row slice into LDS (once) ----
    const float* orib = ori + ((size_t)b * KPTS + (size_t)ns * RBLK) * 3;
#pragma unroll
    for (int i = 0; i < 4; ++i) {
        const int rr = tid + i * 256;
        const float* op = orib + (size_t)rr * 3;
        float x = op[0], y = op[1], z = op[2];
        float oo = x * x + y * y + z * z;
        _Float16 hx = (_Float16)x, hy = (_Float16)y, hz = (_Float16)z;
        _Float16 lx = (_Float16)(x - (float)hx);
        _Float16 ly = (_Float16)(y - (float)hy);
        _Float16 lz = (_Float16)(z - (float)hz);
        _Float16 oh = (_Float16)oo;
        _Float16 ol = (_Float16)(oo - (float)oh);
        half8 a0 = {hx, hy, hz, hx, hy, hz, lx, ly};
        half8 a1 = {lz, oh, ol, Z, Z, Z, Z, Z};
        const int off = ((rr >> 5) << 9) + ((rr & 31) << 3);
        *(half8*)(&sA[off])       = a0;
        *(half8*)(&sA[off + 256]) = a1;
    }
    __syncthreads();   // the only barrier

    f32x16 zc;
#pragma unroll
    for (int i = 0; i < 16; ++i) zc[i] = 0.0f;

    float rm0 = __builtin_huge_valf(), rm1 = __builtin_huge_valf();
    float rm2 = __builtin_huge_valf(), rm3 = __builtin_huge_valf();

    // Tile-order rotation: rho(t) = t ^ k8; byte offset (t<<10)^Kb since
    // XOR distributes over the shift. Mixes bid bits so co-CU blocks differ
    // under both consecutive and strided dispatch mappings.
    const int Kb = (((bid ^ (bid >> 2) ^ (bid >> 8)) & 3) << 13);
    const char* aplb = (const char*)sA + (lane << 4);

    // ---- prologue: tiles rho(0), rho(1); MFMA4 on rho(0) ----
    half8 af  = *(const half8*)(aplb + Kb);            // rho(0)
    half8 afn = *(const half8*)(aplb + (1024 ^ Kb));   // rho(1)
    f32x16 d0, d1, d2, d3;
    asm volatile(
        "s_setprio 1\n\t"
        "v_mfma_f32_32x32x16_f16 %0, %4, %5, %9\n\t"
        "v_mfma_f32_32x32x16_f16 %1, %4, %6, %9\n\t"
        "v_mfma_f32_32x32x16_f16 %2, %4, %7, %9\n\t"
        "v_mfma_f32_32x32x16_f16 %3, %4, %8, %9\n\t"
        "s_setprio 0\n\t"
        "s_nop 7\n\ts_nop 7"
        : "=&v"(d0), "=&v"(d1), "=&v"(d2), "=&v"(d3)
        : "v"(af), "v"(bf0), "v"(bf1), "v"(bf2), "v"(bf3), "v"(zc));
    af = afn;

    // ---- pipelined loop: prefetch rho(t+1); fold(t-1) ∥ MFMA(t) ----
#pragma unroll
    for (int t = 1; t < TSLICE - 1; ++t) {
        half8 afn2 = *(const half8*)(aplb + (((t + 1) << 10) ^ Kb));
        FOLD17(rm0, d0);                    // tile t-1
        FOLD17(rm1, d1);
        MFMA2P(d0, d1, af, bf0, bf1, zc);   // tile t
        FOLD17(rm2, d2);                    // tile t-1
        FOLD17(rm3, d3);
        MFMA2P(d2, d3, af, bf2, bf3, zc);   // tile t
        af = afn2;
    }

    // ---- epilogue: tile 31 MFMAs + final folds ----
    FOLD17(rm0, d0);                        // tile 30
    FOLD17(rm1, d1);
    MFMA2P(d0, d1, af, bf0, bf1, zc);       // tile 31
    FOLD17(rm2, d2);                        // tile 30
    FOLD17(rm3, d3);
    MFMA2P(d2, d3, af, bf2, bf3, zc);       // tile 31
    asm volatile("s_nop 7\n\ts_nop 7" ::: );
    FOLD17(rm0, d0);
    FOLD17(rm1, d1);
    FOLD17(rm2, d2);
    FOLD17(rm3, d3);

    // complete the 32-row min (lanes l, l^32 cover complementary rows, same col)
    rm0 = fminf(rm0, __shfl_xor(rm0, 32, 64));
    rm1 = fminf(rm1, __shfl_xor(rm1, 32, 64));
    rm2 = fminf(rm2, __shfl_xor(rm2, 32, 64));
    rm3 = fminf(rm3, __shfl_xor(rm3, 32, 64));

    // plain coalesced partial stores part[ns][b][col] (no init required)
    float* p = part + ((size_t)ns * BATCH + b) * KPTS;
    if (hk == 0) {
        p[m0]      = fmaxf(rm0 + aa0, 0.0f);
        p[m0 + 32] = fmaxf(rm1 + aa1, 0.0f);
        p[m0 + 64] = fmaxf(rm2 + aa2, 0.0f);
        p[m0 + 96] = fmaxf(rm3 + aa3, 0.0f);
    }
}

// 8 blocks (one per batch), 1024 threads: min over slices, max over columns.
__global__ __launch_bounds__(1024) void reduceB(const float* __restrict__ part,
                                                const float* __restrict__ w,
                                                float* __restrict__ out) {
    const int b = blockIdx.x;
    const int tid = threadIdx.x;

    float mx = 0.0f;   // partials are clamped nonneg
#pragma unroll
    for (int h = 0; h < 2; ++h) {
        const int c4 = tid + h * 1024;
        float4 v[NSPLIT];
#pragma unroll
        for (int s = 0; s < NSPLIT; ++s)
            v[s] = *(const float4*)(part + ((size_t)s * BATCH + b) * KPTS + (size_t)c4 * 4);
        float4 mn = v[0];
#pragma unroll
        for (int s = 1; s < NSPLIT; ++s) {
            mn.x = fminf(mn.x, v[s].x); mn.y = fminf(mn.y, v[s].y);
            mn.z = fminf(mn.z, v[s].z); mn.w = fminf(mn.w, v[s].w);
        }
        mx = fmaxf(mx, fmaxf(fmaxf(mn.x, mn.y), fmaxf(mn.z, mn.w)));
    }

#pragma unroll
    for (int off = 32; off; off >>= 1)
        mx = fmaxf(mx, __shfl_xor(mx, off, 64));

    __shared__ float red[16];
    if ((tid & 63) == 0) red[tid >> 6] = mx;
    __syncthreads();
    if (tid == 0) {
        float m2 = red[0];
#pragma unroll
        for (int i = 1; i < 16; ++i) m2 = fmaxf(m2, red[i]);
        atomicAdd(out, m2 * w[b] * (1.0f / BATCH));
    }
}

extern "C" void kernel_launch(void* const* d_in, const int* in_sizes, int n_in,
                              void* d_out, int out_size, void* d_ws, size_t ws_size,
                              hipStream_t stream) {
    const float* adv = (const float*)d_in[0];   // [B, K, 3]
    const float* ori = (const float*)d_in[1];   // [B, K, 3]
    const float* w   = (const float*)d_in[2];   // [B]
    float* out = (float*)d_out;
    float* part = (float*)d_ws;                 // NSPLIT*B*K floats = 2 MB

    hausdorff<<<BATCH * MCHUNK * NSPLIT, 256, 0, stream>>>(adv, ori, part, out);
    reduceB<<<BATCH, 1024, 0, stream>>>((const float*)part, w, out);
}

// Round 13
// 74.727 us; speedup vs baseline: 1.0396x; 1.0396x over previous
//
#include <hip/hip_runtime.h>

// Hausdorff adv2ori via MFMA: B=8, K=8192.
// dist(n,m) = oo_n + aa_m - 2*o.a ; C = mfma(A',B') = oo_n - 2*o.a (fp16 hi/lo split)
// loss = mean_b( w_b * max_m min_n dist )
//
// R12 post-mortem: accounting via R9 (195.2 = 40.5 fill + 149.8 diag + 4.9
// gaps) => gaps ~5us, so main is ~32us single-shot vs 18.7us/rep amplified.
// R9's VGPR_Count=52 (arch) with a >110-reg liveset => f32x16 d-values live in
// AGPRs; every asm-block boundary ("v" scalar ins of FOLD) forces 16
// v_accvgpr_read copies -> hidden VALU tax in all R10-R12 variants.
// R13: one asm block per tile = {4 MFMA (dest PINNED v64..v127, C=inline 0),
// 2 s_nop 7, 4 in-place min3-folds}. Pinned physical regs + explicit clobbers
// make cross-file copies impossible; zc deleted (C=0 inline const, -16 regs);
// compiler-side ds_read prefetch at full-tile distance; unroll 2 (~2KB code,
// 5x smaller cold-icache footprint). Grid/staging/reduceB = proven R8 frame.

#define KPTS 8192
#define BATCH 8
#define NSPLIT 8
#define RBLK (KPTS / NSPLIT)          // 1024 rows per slice
#define TSLICE (RBLK / 32)            // 32 MFMA row-tiles per slice
#define CBLK 512                      // adv columns per block (4 waves x 128)
#define MCHUNK (KPTS / CBLK)          // 16

typedef _Float16 half8 __attribute__((ext_vector_type(8)));

// One tile: 4 MFMAs into pinned v[64:127] (C = inline 0), hazard nops, then
// in-place min3 folds (d is dead after; next tile's MFMAs rewrite it).
// rm0..rm3 are "+v" scalars. No f32x16 ever crosses an asm boundary.
#define TILE_ASM(af_, rm0_, rm1_, rm2_, rm3_, b0_, b1_, b2_, b3_)             \
    asm volatile(                                                             \
        "v_mfma_f32_32x32x16_f16 v[64:79], %4, %5, 0\n\t"                     \
        "v_mfma_f32_32x32x16_f16 v[80:95], %4, %6, 0\n\t"                     \
        "v_mfma_f32_32x32x16_f16 v[96:111], %4, %7, 0\n\t"                    \
        "v_mfma_f32_32x32x16_f16 v[112:127], %4, %8, 0\n\t"                   \
        "s_nop 7\n\t"                                                         \
        "s_nop 7\n\t"                                                         \
        "v_min3_f32 v64, v64, v65, v66\n\t"                                   \
        "v_min3_f32 v67, v67, v68, v69\n\t"                                   \
        "v_min3_f32 v70, v70, v71, v72\n\t"                                   \
        "v_min3_f32 v73, v73, v74, v75\n\t"                                   \
        "v_min3_f32 v76, v76, v77, v78\n\t"                                   \
        "v_min3_f32 v79, v79, %0, v64\n\t"                                    \
        "v_min3_f32 v67, v67, v70, v73\n\t"                                   \
        "v_min3_f32 %0, v76, v79, v67\n\t"                                    \
        "v_min3_f32 v80, v80, v81, v82\n\t"                                   \
        "v_min3_f32 v83, v83, v84, v85\n\t"                                   \
        "v_min3_f32 v86, v86, v87, v88\n\t"                                   \
        "v_min3_f32 v89, v89, v90, v91\n\t"                                   \
        "v_min3_f32 v92, v92, v93, v94\n\t"                                   \
        "v_min3_f32 v95, v95, %1, v80\n\t"                                    \
        "v_min3_f32 v83, v83, v86, v89\n\t"                                   \
        "v_min3_f32 %1, v92, v95, v83\n\t"                                    \
        "v_min3_f32 v96, v96, v97, v98\n\t"                                   \
        "v_min3_f32 v99, v99, v100, v101\n\t"                                 \
        "v_min3_f32 v102, v102, v103, v104\n\t"                               \
        "v_min3_f32 v105, v105, v106, v107\n\t"                               \
        "v_min3_f32 v108, v108, v109, v110\n\t"                               \
        "v_min3_f32 v111, v111, %2, v96\n\t"                                  \
        "v_min3_f32 v99, v99, v102, v105\n\t"                                 \
        "v_min3_f32 %2, v108, v111, v99\n\t"                                  \
        "v_min3_f32 v112, v112, v113, v114\n\t"                               \
        "v_min3_f32 v115, v115, v116, v117\n\t"                               \
        "v_min3_f32 v118, v118, v119, v120\n\t"                               \
        "v_min3_f32 v121, v121, v122, v123\n\t"                               \
        "v_min3_f32 v124, v124, v125, v126\n\t"                               \
        "v_min3_f32 v127, v127, %3, v112\n\t"                                 \
        "v_min3_f32 v115, v115, v118, v121\n\t"                               \
        "v_min3_f32 %3, v124, v127, v115"                                     \
        : "+v"(rm0_), "+v"(rm1_), "+v"(rm2_), "+v"(rm3_)                      \
        : "v"(af_), "v"(b0_), "v"(b1_), "v"(b2_), "v"(b3_)                    \
        : "v64","v65","v66","v67","v68","v69","v70","v71",                    \
          "v72","v73","v74","v75","v76","v77","v78","v79",                    \
          "v80","v81","v82","v83","v84","v85","v86","v87",                    \
          "v88","v89","v90","v91","v92","v93","v94","v95",                    \
          "v96","v97","v98","v99","v100","v101","v102","v103",                \
          "v104","v105","v106","v107","v108","v109","v110","v111",            \
          "v112","v113","v114","v115","v116","v117","v118","v119",            \
          "v120","v121","v122","v123","v124","v125","v126","v127")

__global__ __launch_bounds__(256, 4) void hausdorff(const float* __restrict__ adv,
                                                    const float* __restrict__ ori,
                                                    float* __restrict__ part,
                                                    float* __restrict__ out) {
    // Tile-planar A' slice: tile t at halfs [t*512,(t+1)*512); lane reads
    // byte lane*16 -> linear, conflict-free. +1 pad tile for last prefetch.
    __shared__ _Float16 sA[(TSLICE + 1) * 512];   // 33 KB -> 4 blocks/CU

    const int bid  = blockIdx.x;          // grid = 8 * 16 * 8 = 1024
    const int b    = bid >> 7;
    const int mc   = (bid >> 3) & (MCHUNK - 1);
    const int ns   = bid & 7;
    const int tid  = threadIdx.x;
    const int lane = tid & 63;
    const int wv   = tid >> 6;
    const int r    = lane & 31;
    const int hk   = lane >> 5;

    if (bid == 0 && tid == 0) out[0] = 0.0f;   // for reduceB's atomicAdd

    const _Float16 Z = (_Float16)0.0f, ONE = (_Float16)1.0f;

    // ---- B-fragments + aa for this wave's 4 column groups ----
    const float* advb = adv + (size_t)b * KPTS * 3;
    const int m0 = mc * CBLK + wv * 128 + r;
    half8 bf0, bf1, bf2, bf3;
    float aa0, aa1, aa2, aa3;
#pragma unroll
    for (int i = 0; i < 4; ++i) {
        const int m = m0 + 32 * i;
        float ax = advb[3 * m], ay = advb[3 * m + 1], az = advb[3 * m + 2];
        float aa = ax * ax + ay * ay + az * az;
        float tx = -2.f * ax, ty = -2.f * ay, tz = -2.f * az;
        _Float16 bx = (_Float16)tx, by = (_Float16)ty, bz = (_Float16)tz;
        _Float16 cx = (_Float16)(tx - (float)bx);
        _Float16 cy = (_Float16)(ty - (float)by);
        _Float16 cz = (_Float16)(tz - (float)bz);
        half8 h0 = {bx, by, bz, cx, cy, cz, bx, by};
        half8 h1 = {bz, ONE, ONE, Z, Z, Z, Z, Z};
        half8 bi = hk ? h1 : h0;
        if (i == 0) { bf0 = bi; aa0 = aa; }
        else if (i == 1) { bf1 = bi; aa1 = aa; }
        else if (i == 2) { bf2 = bi; aa2 = aa; }
        else { bf3 = bi; aa3 = aa; }
    }

    // ---- stage + convert this block's 1024-row slice into LDS (once) ----
    const float* orib = ori + ((size_t)b * KPTS + (size_t)ns * RBLK) * 3;
#pragma unroll
    for (int i = 0; i < 4; ++i) {
        const int rr = tid + i * 256;
        const float* op = orib + (size_t)rr * 3;
        float x = op[0], y = op[1], z = op[2];
        float oo = x * x + y * y + z * z;
        _Float16 hx = (_Float16)x, hy = (_Float16)y, hz = (_Float16)z;
        _Float16 lx = (_Float16)(x - (float)hx);
        _Float16 ly = (_Float16)(y - (float)hy);
        _Float16 lz = (_Float16)(z - (float)hz);
        _Float16 oh = (_Float16)oo;
        _Float16 ol = (_Float16)(oo - (float)oh);
        half8 a0 = {hx, hy, hz, hx, hy, hz, lx, ly};
        half8 a1 = {lz, oh, ol, Z, Z, Z, Z, Z};
        const int off = ((rr >> 5) << 9) + ((rr & 31) << 3);
        *(half8*)(&sA[off])       = a0;
        *(half8*)(&sA[off + 256]) = a1;
    }
    __syncthreads();   // the only barrier

    float rm0 = __builtin_huge_valf(), rm1 = __builtin_huge_valf();
    float rm2 = __builtin_huge_valf(), rm3 = __builtin_huge_valf();

    const _Float16* apl = sA + lane * 8;   // lane's 16B within tile 0

    // Full-tile prefetch distance (R10-proven): ds_read(t+1) issued before
    // tile t's asm; consumed next iteration. Pad tile absorbs t=31 overread.
    half8 af = *(const half8*)apl;
#pragma unroll 2
    for (int t = 0; t < TSLICE; ++t) {
        half8 afn = *(const half8*)(apl + (size_t)(t + 1) * 512);
        TILE_ASM(af, rm0, rm1, rm2, rm3, bf0, bf1, bf2, bf3);
        af = afn;
    }

    // complete the 32-row min (lanes l, l^32 cover complementary rows, same col)
    rm0 = fminf(rm0, __shfl_xor(rm0, 32, 64));
    rm1 = fminf(rm1, __shfl_xor(rm1, 32, 64));
    rm2 = fminf(rm2, __shfl_xor(rm2, 32, 64));
    rm3 = fminf(rm3, __shfl_xor(rm3, 32, 64));

    // plain coalesced partial stores part[ns][b][col] (no init required)
    float* p = part + ((size_t)ns * BATCH + b) * KPTS;
    if (hk == 0) {
        p[m0]      = fmaxf(rm0 + aa0, 0.0f);
        p[m0 + 32] = fmaxf(rm1 + aa1, 0.0f);
        p[m0 + 64] = fmaxf(rm2 + aa2, 0.0f);
        p[m0 + 96] = fmaxf(rm3 + aa3, 0.0f);
    }
}

// 8 blocks (one per batch), 1024 threads: min over slices, max over columns.
__global__ __launch_bounds__(1024) void reduceB(const float* __restrict__ part,
                                                const float* __restrict__ w,
                                                float* __restrict__ out) {
    const int b = blockIdx.x;
    const int tid = threadIdx.x;

    float mx = 0.0f;   // partials are clamped nonneg
#pragma unroll
    for (int h = 0; h < 2; ++h) {
        const int c4 = tid + h * 1024;
        float4 v[NSPLIT];
#pragma unroll
        for (int s = 0; s < NSPLIT; ++s)
            v[s] = *(const float4*)(part + ((size_t)s * BATCH + b) * KPTS + (size_t)c4 * 4);
        float4 mn = v[0];
#pragma unroll
        for (int s = 1; s < NSPLIT; ++s) {
            mn.x = fminf(mn.x, v[s].x); mn.y = fminf(mn.y, v[s].y);
            mn.z = fminf(mn.z, v[s].z); mn.w = fminf(mn.w, v[s].w);
        }
        mx = fmaxf(mx, fmaxf(fmaxf(mn.x, mn.y), fmaxf(mn.z, mn.w)));
    }

#pragma unroll
    for (int off = 32; off; off >>= 1)
        mx = fmaxf(mx, __shfl_xor(mx, off, 64));

    __shared__ float red[16];
    if ((tid & 63) == 0) red[tid >> 6] = mx;
    __syncthreads();
    if (tid == 0) {
        float m2 = red[0];
#pragma unroll
        for (int i = 1; i < 16; ++i) m2 = fmaxf(m2, red[i]);
        atomicAdd(out, m2 * w[b] * (1.0f / BATCH));
    }
}

extern "C" void kernel_launch(void* const* d_in, const int* in_sizes, int n_in,
                              void* d_out, int out_size, void* d_ws, size_t ws_size,
                              hipStream_t stream) {
    const float* adv = (const float*)d_in[0];   // [B, K, 3]
    const float* ori = (const float*)d_in[1];   // [B, K, 3]
    const float* w   = (const float*)d_in[2];   // [B]
    float* out = (float*)d_out;
    float* part = (float*)d_ws;                 // NSPLIT*B*K floats = 2 MB

    hausdorff<<<BATCH * MCHUNK * NSPLIT, 256, 0, stream>>>(adv, ori, part, out);
    reduceB<<<BATCH, 1024, 0, stream>>>((const float*)part, w, out);
}